// Round 7
// baseline (745.473 us; speedup 1.0000x reference)
//
#include <hip/hip_runtime.h>
#include <hip/hip_bf16.h>
#include <math.h>

#define B_TOTAL 131072
#define NX 64
#define H 512
#define LD 8
#define NT 45          // 1 + 8 + 36
#define NSTEPS 20

#define NTH 512        // 8 waves
#define BM 128         // rows per block (1 block/CU, 256-reg budget: no spill)
#define ASTR 520       // bf16 elements per activation row (1040B stride: 2-way bank alias only)

// ws layout (bf16 elements). GEMM weights are K-CHUNKED: W[kc][n][32], chunk = 32 k-elems.
#define OFF_EW1T 0                    // [2][512][32]   (K=64)
#define OFF_EW2T 32768                // [16][512][32]
#define OFF_DW2T 294912               // [16][512][32]
#define OFF_DW3T 557056               // [16][64][32]
#define WS_ELEMS 589824
#define OFF_W3HI 589824               // [16][512] flat: bf16 hi part of eW3^T (rows 8..15 zero)
#define OFF_W3LO 598016               // [16][512] flat: bf16 lo correction
#define WS_ELEMS2 606208              // * 2 bytes
#define ZT_OFF_BYTES (WS_ELEMS2 * 2)
#define WS_NEW_BYTES (ZT_OFF_BYTES + (size_t)B_TOTAL * LD * 4)

typedef __attribute__((ext_vector_type(8))) short short8;
typedef __attribute__((ext_vector_type(4))) float f32x4;

__device__ __forceinline__ ushort f2bf(float f) {
    union { float f; uint u; } v; v.f = f;
    uint u = v.u;
    u += 0x7fff + ((u >> 16) & 1);          // RNE
    return (ushort)(u >> 16);
}
__device__ __forceinline__ float bf2f(ushort s) {
    union { uint u; float f; } v; v.u = ((uint)s) << 16;
    return v.f;
}
__device__ __forceinline__ float silu_f(float v) {
    return v / (1.0f + __expf(-v));
}

// ---------------- weight prep: fp32 row-major [k][n] -> bf16 chunked W^T [kc][n][32] ----------------
__global__ void prep_weights(const float* __restrict__ eW1, const float* __restrict__ eW2,
                             const float* __restrict__ dW2, const float* __restrict__ dW3,
                             const float* __restrict__ eW3, short* __restrict__ ws) {
    const int id = blockIdx.x * 256 + threadIdx.x;
    if (id < OFF_EW2T) {                               // eW1c [2][512][32]
        const int kc = id >> 14, n = (id >> 5) & 511, kk = id & 31;
        ws[id] = (short)f2bf(eW1[(kc * 32 + kk) * H + n]);
    } else if (id < OFF_DW2T) {                        // eW2c [16][512][32]
        const int j = id - OFF_EW2T;
        const int kc = j >> 14, n = (j >> 5) & 511, kk = j & 31;
        ws[id] = (short)f2bf(eW2[(kc * 32 + kk) * H + n]);
    } else if (id < OFF_DW3T) {                        // dW2c [16][512][32]
        const int j = id - OFF_DW2T;
        const int kc = j >> 14, n = (j >> 5) & 511, kk = j & 31;
        ws[id] = (short)f2bf(dW2[(kc * 32 + kk) * H + n]);
    } else if (id < WS_ELEMS) {                        // dW3c [16][64][32]
        const int j = id - OFF_DW3T;
        const int kc = j >> 11, n = (j >> 5) & 63, kk = j & 31;
        ws[id] = (short)f2bf(dW3[(kc * 32 + kk) * NX + n]);
    } else if (id < OFF_W3LO) {                        // eW3T hi [16][512] flat
        const int j = id - OFF_W3HI, n = j >> 9, k = j & 511;
        const float v = (n < LD) ? eW3[k * LD + n] : 0.f;
        ws[id] = (short)f2bf(v);
    } else if (id < WS_ELEMS2) {                       // eW3T lo
        const int j = id - OFF_W3LO, n = j >> 9, k = j & 511;
        const float v = (n < LD) ? eW3[k * LD + n] : 0.f;
        const float hi = bf2f(f2bf(v));
        ws[id] = (short)f2bf(v - hi);
    }
}

// ---------------- GEMM: act[128][K] (LDS bf16) x W(KxN) via chunked W^T; 1x8 wave grid ----------------
// Wave w owns ALL 128 rows x cols [w*64, w*64+64) -> B loaded exactly once per block,
// each B-frag load one contiguous 1KB segment. Ping-pong register prefetch of B chunks.
// Budget: acc 128 (AGPR) + B 64 + A 4 + addr ~15 = ~215 < 256 (launch_bounds 512,2).
template <int K, int N>
__device__ __forceinline__ void gemm_chunked(const short (*act)[ASTR], const short* __restrict__ WTc,
                                             f32x4 (&acc)[8][4], int w, int lm, int q) {
    constexpr int NC = K / 32;              // 2 or 16 (even)
    constexpr int CS = N * 32;              // elements per chunk
    const short* bp = WTc + (w * 64 + lm) * 32 + q * 8;
    short8 be[4], bo[4];
#pragma unroll
    for (int tt = 0; tt < 4; ++tt) be[tt] = *(const short8*)(bp + tt * 512);
#pragma unroll 1
    for (int kc = 0; kc < NC; kc += 2) {
        {   // prefetch odd chunk
            const short* p = bp + (kc + 1) * CS;
#pragma unroll
            for (int tt = 0; tt < 4; ++tt) bo[tt] = *(const short8*)(p + tt * 512);
        }
        {   // compute even chunk (A one mt at a time: 8 ds_reads + 32 MFMAs)
            const int k0 = kc * 32 + q * 8;
#pragma unroll
            for (int mt = 0; mt < 8; ++mt) {
                short8 a = *(const short8*)&act[mt * 16 + lm][k0];
#pragma unroll
                for (int tt = 0; tt < 4; ++tt)
                    acc[mt][tt] = __builtin_amdgcn_mfma_f32_16x16x32_bf16(a, be[tt], acc[mt][tt], 0, 0, 0);
            }
        }
        if (kc + 2 < NC) {   // prefetch next even chunk
            const short* p = bp + (kc + 2) * CS;
#pragma unroll
            for (int tt = 0; tt < 4; ++tt) be[tt] = *(const short8*)(p + tt * 512);
        }
        {   // compute odd chunk
            const int k0 = (kc + 1) * 32 + q * 8;
#pragma unroll
            for (int mt = 0; mt < 8; ++mt) {
                short8 a = *(const short8*)&act[mt * 16 + lm][k0];
#pragma unroll
                for (int tt = 0; tt < 4; ++tt)
                    acc[mt][tt] = __builtin_amdgcn_mfma_f32_16x16x32_bf16(a, bo[tt], acc[mt][tt], 0, 0, 0);
            }
        }
    }
}

// ---------------- bias + LayerNorm + SiLU epilogue, 1x8 grid over 128 rows ----------------
// C-layout: value (row = mt*16 + q*4 + r, col = w*64 + tt*16 + lm). In-place safe (stores after barriers).
__device__ __forceinline__ void ln_epi128(f32x4 (&acc)[8][4],
        const float* __restrict__ bias, const float* __restrict__ g, const float* __restrict__ be,
        short (*act)[ASTR], float (*p1)[8], float (*p2)[8], float (*rstat)[2],
        int w, int lane, int tid) {
    const int lm = lane & 15, q = lane >> 4;
    float cb[4], cg[4], cbe[4];
#pragma unroll
    for (int tt = 0; tt < 4; ++tt) {
        const int c = w * 64 + tt * 16 + lm;
        cb[tt] = bias[c]; cg[tt] = g[c]; cbe[tt] = be[c];
    }
#pragma unroll
    for (int mt = 0; mt < 8; ++mt) {
        float s1[4] = {0.f, 0.f, 0.f, 0.f}, s2[4] = {0.f, 0.f, 0.f, 0.f};
#pragma unroll
        for (int tt = 0; tt < 4; ++tt)
#pragma unroll
            for (int r = 0; r < 4; ++r) {
                float v = acc[mt][tt][r] + cb[tt];
                acc[mt][tt][r] = v;
                s1[r] += v;
                s2[r] += v * v;
            }
#pragma unroll
        for (int m = 1; m < 16; m <<= 1) {
#pragma unroll
            for (int r = 0; r < 4; ++r) {
                s1[r] += __shfl_xor(s1[r], m);
                s2[r] += __shfl_xor(s2[r], m);
            }
        }
        if (lm == 0) {
#pragma unroll
            for (int r = 0; r < 4; ++r) {
                const int row = mt * 16 + q * 4 + r;
                p1[row][w] = s1[r];
                p2[row][w] = s2[r];
            }
        }
    }
    __syncthreads();
    if (tid < BM) {
        float a = 0.f, b2 = 0.f;
#pragma unroll
        for (int j = 0; j < 8; ++j) { a += p1[tid][j]; b2 += p2[tid][j]; }
        const float mean = a * (1.0f / H);
        rstat[tid][0] = mean;
        rstat[tid][1] = rsqrtf(b2 * (1.0f / H) - mean * mean + 1e-5f);
    }
    __syncthreads();
#pragma unroll
    for (int mt = 0; mt < 8; ++mt) {
#pragma unroll
        for (int r = 0; r < 4; ++r) {
            const int row = mt * 16 + q * 4 + r;
            const float mu = rstat[row][0], rs = rstat[row][1];
#pragma unroll
            for (int tt = 0; tt < 4; ++tt) {
                const float v = (acc[mt][tt][r] - mu) * rs * cg[tt] + cbe[tt];
                act[row][w * 64 + tt * 16 + lm] = (short)f2bf(silu_f(v));
            }
        }
    }
    __syncthreads();
}

// ==================== K1: x0 -> encoder -> Euler -> z_t ====================
__global__ __launch_bounds__(NTH, 2) void sindy_enc_kernel(
        const float* __restrict__ x0, const float* __restrict__ logdt,
        const float* __restrict__ eb1, const float* __restrict__ eg1, const float* __restrict__ ebe1,
        const float* __restrict__ eb2, const float* __restrict__ eg2, const float* __restrict__ ebe2,
        const float* __restrict__ eb3, const float* __restrict__ Xi,
        const short* __restrict__ wsb, float* __restrict__ zt) {
    __shared__ __align__(16) short act[BM][ASTR];          // 133,120 B
    __shared__ __align__(16) float scratch[4096];          // 16 KB: p1|p2 or partial[4][128][8]
    __shared__ float rstat[BM][2];
    __shared__ float dtb[BM];
    __shared__ float xis[NT * LD];
    float (*p1)[8] = (float(*)[8])scratch;                       // [128][8]
    float (*p2)[8] = (float(*)[8])(scratch + 1024);              // [128][8]
    float (*partial)[BM][LD] = (float(*)[BM][LD])scratch;        // [4][128][8] (time-disjoint)

    const int tid = threadIdx.x;
    const int w = tid >> 6, lane = tid & 63, lm = lane & 15, q = lane >> 4;
    const int row0 = blockIdx.x * BM;

    if (tid < NT * LD) xis[tid] = Xi[tid];
    if (tid < BM) dtb[tid] = logdt[row0 + tid] * (1.0f / NSTEPS);
    {   // stage x0 tile fp32 -> bf16 LDS (128 rows x 64 cols): thread loads 16 floats
        const int r = tid >> 2, c16 = (tid & 3) * 16;
        const float* xr = &x0[(row0 + r) * NX + c16];
#pragma unroll
        for (int h = 0; h < 2; ++h) {
            const float4 va = *(const float4*)(xr + h * 8);
            const float4 vb = *(const float4*)(xr + h * 8 + 4);
            short8 sv;
            sv[0] = (short)f2bf(va.x); sv[1] = (short)f2bf(va.y);
            sv[2] = (short)f2bf(va.z); sv[3] = (short)f2bf(va.w);
            sv[4] = (short)f2bf(vb.x); sv[5] = (short)f2bf(vb.y);
            sv[6] = (short)f2bf(vb.z); sv[7] = (short)f2bf(vb.w);
            *(short8*)&act[r][c16 + h * 8] = sv;
        }
    }
    __syncthreads();

    // ---- enc1: 64 -> 512 ----
    {
        f32x4 acc[8][4];
#pragma unroll
        for (int mt = 0; mt < 8; ++mt)
#pragma unroll
            for (int tt = 0; tt < 4; ++tt) acc[mt][tt] = (f32x4){0.f, 0.f, 0.f, 0.f};
        gemm_chunked<NX, H>(act, wsb + OFF_EW1T, acc, w, lm, q);
        ln_epi128(acc, eb1, eg1, ebe1, act, p1, p2, rstat, w, lane, tid);
    }

    // ---- enc2: 512 -> 512 ----
    {
        f32x4 acc[8][4];
#pragma unroll
        for (int mt = 0; mt < 8; ++mt)
#pragma unroll
            for (int tt = 0; tt < 4; ++tt) acc[mt][tt] = (f32x4){0.f, 0.f, 0.f, 0.f};
        gemm_chunked<H, H>(act, wsb + OFF_EW2T, acc, w, lm, q);
        ln_epi128(acc, eb2, eg2, ebe2, act, p1, p2, rstat, w, lane, tid);
    }

    // ---- enc3: 512 -> 8 via MFMA, hi/lo bf16 weight split (~fp32 weight precision) ----
    // wave w: kq = w&3 (128 k), mh = w>>2 (64-row half = 4 m-tiles). 32 MFMA/wave.
    float zr0, zr1;
    {
        const short* W3H = wsb + OFF_W3HI;
        const short* W3L = wsb + OFF_W3LO;
        const int kq = w & 3, mh = w >> 2;
        f32x4 a3[4];
#pragma unroll
        for (int i = 0; i < 4; ++i) a3[i] = (f32x4){0.f, 0.f, 0.f, 0.f};
#pragma unroll
        for (int kc = 0; kc < 4; ++kc) {
            const int k0 = kq * 128 + kc * 32 + q * 8;
            short8 bh = *(const short8*)&W3H[lm * H + k0];
            short8 bl = *(const short8*)&W3L[lm * H + k0];
#pragma unroll
            for (int i = 0; i < 4; ++i) {
                short8 a = *(const short8*)&act[mh * 64 + i * 16 + lm][k0];
                a3[i] = __builtin_amdgcn_mfma_f32_16x16x32_bf16(a, bh, a3[i], 0, 0, 0);
                a3[i] = __builtin_amdgcn_mfma_f32_16x16x32_bf16(a, bl, a3[i], 0, 0, 0);
            }
        }
        if (lm < 8) {
#pragma unroll
            for (int i = 0; i < 4; ++i)
#pragma unroll
                for (int r = 0; r < 4; ++r)
                    partial[kq][mh * 64 + i * 16 + q * 4 + r][lm] = a3[i][r];
        }
        __syncthreads();
        const int r = tid >> 3, c = tid & 7;
        float s0 = 0.f, sB = 0.f;
#pragma unroll
        for (int k2 = 0; k2 < 4; ++k2) {
            s0 += partial[k2][r][c];
            sB += partial[k2][r + 64][c];
        }
        zr0 = tanhf(s0 + eb3[c]);
        zr1 = tanhf(sB + eb3[c]);
    }

    // ---- SINDy Euler: barrier-free, register/shuffle form; 2 rows per thread ----
    {
        const int r = tid >> 3, c = tid & 7;
        const int lbase = lane & ~7;
        float xr[NT];
#pragma unroll
        for (int t = 0; t < NT; ++t) xr[t] = xis[t * LD + c];
        const float dt0 = dtb[r], dt1 = dtb[r + 64];
        float zc0 = zr0, zc1 = zr1;
        for (int st = 0; st < NSTEPS; ++st) {
            float z0[LD], z1[LD];
#pragma unroll
            for (int j = 0; j < LD; ++j) {
                z0[j] = __shfl(zc0, lbase + j);
                z1[j] = __shfl(zc1, lbase + j);
            }
            float zd0 = xr[0], zd1 = xr[0];
#pragma unroll
            for (int j = 0; j < LD; ++j) {
                zd0 += z0[j] * xr[1 + j];
                zd1 += z1[j] * xr[1 + j];
            }
            int idx = 1 + LD;
#pragma unroll
            for (int i = 0; i < LD; ++i)
#pragma unroll
                for (int j = i; j < LD; ++j) {
                    zd0 += z0[i] * z0[j] * xr[idx];
                    zd1 += z1[i] * z1[j] * xr[idx];
                    ++idx;
                }
            zc0 += zd0 * dt0;
            zc1 += zd1 * dt1;
        }
        zt[row0 * LD + tid] = zc0;
        zt[row0 * LD + 512 + tid] = zc1;
    }
}

// ==================== K2: z_t -> decoder -> out ====================
__global__ __launch_bounds__(NTH, 2) void sindy_dec_kernel(
        const float* __restrict__ zt,
        const float* __restrict__ dW1, const float* __restrict__ db1,
        const float* __restrict__ dg1, const float* __restrict__ dbe1,
        const float* __restrict__ db2, const float* __restrict__ dg2, const float* __restrict__ dbe2,
        const float* __restrict__ db3,
        const short* __restrict__ wsb, float* __restrict__ out) {
    __shared__ __align__(16) short act[BM][ASTR];
    __shared__ float p1[BM][8], p2[BM][8], rstat[BM][2];
    __shared__ __align__(16) float zbuf[BM][LD];
    const int tid = threadIdx.x;
    const int w = tid >> 6, lane = tid & 63, lm = lane & 15, q = lane >> 4;
    const int row0 = blockIdx.x * BM;

    ((float*)zbuf)[tid] = zt[row0 * LD + tid];
    ((float*)zbuf)[tid + 512] = zt[row0 * LD + 512 + tid];
    __syncthreads();

    // ---- dec1: 8 -> 512 (fp32, MFMA-C-layout); 256-reg budget holds acc without spill ----
    {
        f32x4 acc[8][4];
#pragma unroll
        for (int tt = 0; tt < 4; ++tt) {
            const int c = w * 64 + tt * 16 + lm;
            float wk[LD];
#pragma unroll
            for (int k = 0; k < LD; ++k) wk[k] = dW1[k * H + c];
#pragma unroll
            for (int mt = 0; mt < 8; ++mt)
#pragma unroll
                for (int r = 0; r < 4; ++r) {
                    const int row = mt * 16 + q * 4 + r;
                    float s = 0.f;
#pragma unroll
                    for (int k = 0; k < LD; ++k) s += zbuf[row][k] * wk[k];
                    acc[mt][tt][r] = s;
                }
        }
        ln_epi128(acc, db1, dg1, dbe1, act, p1, p2, rstat, w, lane, tid);
    }

    // ---- dec2: 512 -> 512 ----
    {
        f32x4 acc[8][4];
#pragma unroll
        for (int mt = 0; mt < 8; ++mt)
#pragma unroll
            for (int tt = 0; tt < 4; ++tt) acc[mt][tt] = (f32x4){0.f, 0.f, 0.f, 0.f};
        gemm_chunked<H, H>(act, wsb + OFF_DW2T, acc, w, lm, q);
        ln_epi128(acc, db2, dg2, dbe2, act, p1, p2, rstat, w, lane, tid);
    }

    // ---- dec3: 512 -> 64 + bias, fp32 out. Wave w owns rows w*16..w*16+15, all 64 cols. ----
    {
        const short* W3c = wsb + OFF_DW3T;
        const short* bp = W3c + lm * 32 + q * 8;
        f32x4 a4[4];
#pragma unroll
        for (int u = 0; u < 4; ++u) a4[u] = (f32x4){0.f, 0.f, 0.f, 0.f};
        short8 be[4], bo[4];
#pragma unroll
        for (int u = 0; u < 4; ++u) be[u] = *(const short8*)(bp + u * 512);
#pragma unroll 1
        for (int kc = 0; kc < 16; kc += 2) {
            {
                const short* p = bp + (kc + 1) * 2048;
#pragma unroll
                for (int u = 0; u < 4; ++u) bo[u] = *(const short8*)(p + u * 512);
            }
            {
                const int k0 = kc * 32 + q * 8;
                short8 a = *(const short8*)&act[w * 16 + lm][k0];
#pragma unroll
                for (int u = 0; u < 4; ++u)
                    a4[u] = __builtin_amdgcn_mfma_f32_16x16x32_bf16(a, be[u], a4[u], 0, 0, 0);
            }
            if (kc + 2 < 16) {
                const short* p = bp + (kc + 2) * 2048;
#pragma unroll
                for (int u = 0; u < 4; ++u) be[u] = *(const short8*)(p + u * 512);
            }
            {
                const int k0 = (kc + 1) * 32 + q * 8;
                short8 a = *(const short8*)&act[w * 16 + lm][k0];
#pragma unroll
                for (int u = 0; u < 4; ++u)
                    a4[u] = __builtin_amdgcn_mfma_f32_16x16x32_bf16(a, bo[u], a4[u], 0, 0, 0);
            }
        }
#pragma unroll
        for (int u = 0; u < 4; ++u) {
            const int c = u * 16 + lm;
            const float bb = db3[c];
#pragma unroll
            for (int r = 0; r < 4; ++r) {
                const int row = w * 16 + q * 4 + r;
                out[(row0 + row) * NX + c] = a4[u][r] + bb;
            }
        }
    }
}

// =================== fallback (fp32 kernel, no ws needed) ===================
#define FB_R 16
#define FB_STRIDE 520
#define FB_NT 256

__device__ __forceinline__ void fb_ln_silu(float buf[FB_R][FB_STRIDE],
                                           const float* __restrict__ g,
                                           const float* __restrict__ be, int t) {
    const int r = t >> 4, lane = t & 15;
    float s1 = 0.f, s2 = 0.f;
#pragma unroll
    for (int j = 0; j < H / 16; ++j) {
        float v = buf[r][lane + 16 * j];
        s1 += v; s2 += v * v;
    }
#pragma unroll
    for (int m = 8; m >= 1; m >>= 1) {
        s1 += __shfl_xor(s1, m, 16);
        s2 += __shfl_xor(s2, m, 16);
    }
    const float mean = s1 * (1.0f / H);
    const float var = s2 * (1.0f / H) - mean * mean;
    const float rstd = rsqrtf(var + 1e-5f);
#pragma unroll
    for (int j = 0; j < H / 16; ++j) {
        const int c = lane + 16 * j;
        float v = buf[r][c];
        buf[r][c] = silu_f((v - mean) * rstd * g[c] + be[c]);
    }
}

template <int K>
__device__ __forceinline__ void fb_gemmK(const float in[FB_R][FB_STRIDE], float out[FB_R][FB_STRIDE],
                                         const float* __restrict__ W,
                                         const float* __restrict__ b, int t) {
    const int c0 = t, c1 = t + 256;
    float acc0[FB_R], acc1[FB_R];
#pragma unroll
    for (int r = 0; r < FB_R; ++r) { acc0[r] = 0.f; acc1[r] = 0.f; }
    for (int k = 0; k < K; k += 4) {
        const float w00 = W[(k + 0) * H + c0], w10 = W[(k + 0) * H + c1];
        const float w01 = W[(k + 1) * H + c0], w11 = W[(k + 1) * H + c1];
        const float w02 = W[(k + 2) * H + c0], w12 = W[(k + 2) * H + c1];
        const float w03 = W[(k + 3) * H + c0], w13 = W[(k + 3) * H + c1];
#pragma unroll
        for (int r = 0; r < FB_R; ++r) {
            const float4 h = *(const float4*)&in[r][k];
            acc0[r] += h.x * w00 + h.y * w01 + h.z * w02 + h.w * w03;
            acc1[r] += h.x * w10 + h.y * w11 + h.z * w12 + h.w * w13;
        }
    }
    const float b0 = b[c0], b1 = b[c1];
#pragma unroll
    for (int r = 0; r < FB_R; ++r) {
        out[r][c0] = acc0[r] + b0;
        out[r][c1] = acc1[r] + b1;
    }
}

__global__ __launch_bounds__(FB_NT, 2) void sindy_fallback_kernel(
    const float* __restrict__ x0, const float* __restrict__ logdt,
    const float* __restrict__ eW1, const float* __restrict__ eb1,
    const float* __restrict__ eg1, const float* __restrict__ ebe1,
    const float* __restrict__ eW2, const float* __restrict__ eb2,
    const float* __restrict__ eg2, const float* __restrict__ ebe2,
    const float* __restrict__ eW3, const float* __restrict__ eb3,
    const float* __restrict__ dW1, const float* __restrict__ db1,
    const float* __restrict__ dg1, const float* __restrict__ dbe1,
    const float* __restrict__ dW2, const float* __restrict__ db2,
    const float* __restrict__ dg2, const float* __restrict__ dbe2,
    const float* __restrict__ dW3, const float* __restrict__ db3,
    const float* __restrict__ Xi, float* __restrict__ out) {
    __shared__ float sA[FB_R][FB_STRIDE];
    __shared__ float sB[FB_R][FB_STRIDE];
    __shared__ float zbuf[FB_R][LD];
    __shared__ float dtb[FB_R];
    __shared__ float xis[NT * LD];

    const int t = threadIdx.x;
    const int row0 = blockIdx.x * FB_R;

    for (int i = t; i < NT * LD; i += FB_NT) xis[i] = Xi[i];
    if (t < FB_R) dtb[t] = logdt[row0 + t] * (1.0f / NSTEPS);
    {
        const int r = t >> 4, k4 = (t & 15) * 4;
        *(float4*)&sB[r][k4] = *(const float4*)&x0[(row0 + r) * NX + k4];
    }
    __syncthreads();
    fb_gemmK<NX>(sB, sA, eW1, eb1, t);
    __syncthreads();
    fb_ln_silu(sA, eg1, ebe1, t);
    __syncthreads();
    fb_gemmK<H>(sA, sB, eW2, eb2, t);
    __syncthreads();
    fb_ln_silu(sB, eg2, ebe2, t);
    __syncthreads();
    if (t < FB_R * LD) {
        const int r = t >> 3, c = t & 7;
        float acc = 0.f;
        for (int k = 0; k < H; k += 4) {
            const float4 h = *(const float4*)&sB[r][k];
            acc += h.x * eW3[(k + 0) * LD + c] + h.y * eW3[(k + 1) * LD + c] +
                   h.z * eW3[(k + 2) * LD + c] + h.w * eW3[(k + 3) * LD + c];
        }
        zbuf[r][c] = tanhf(acc + eb3[c]);
    }
    __syncthreads();
    for (int s = 0; s < NSTEPS; ++s) {
        float zn = 0.f;
        const int r = t >> 3, c = t & 7;
        if (t < FB_R * LD) {
            float z[LD];
#pragma unroll
            for (int j = 0; j < LD; ++j) z[j] = zbuf[r][j];
            float zd = xis[c];
#pragma unroll
            for (int j = 0; j < LD; ++j) zd += z[j] * xis[(1 + j) * LD + c];
            int idx = 1 + LD;
#pragma unroll
            for (int i = 0; i < LD; ++i)
#pragma unroll
                for (int j = i; j < LD; ++j) {
                    zd += z[i] * z[j] * xis[idx * LD + c];
                    ++idx;
                }
            zn = z[c] + zd * dtb[r];
        }
        __syncthreads();
        if (t < FB_R * LD) zbuf[r][c] = zn;
        __syncthreads();
    }
    {
        const int c0 = t, c1 = t + 256;
        float acc0[FB_R], acc1[FB_R];
#pragma unroll
        for (int r = 0; r < FB_R; ++r) { acc0[r] = 0.f; acc1[r] = 0.f; }
#pragma unroll
        for (int k = 0; k < LD; ++k) {
            const float w0 = dW1[k * H + c0], w1 = dW1[k * H + c1];
#pragma unroll
            for (int r = 0; r < FB_R; ++r) {
                const float zv = zbuf[r][k];
                acc0[r] += zv * w0;
                acc1[r] += zv * w1;
            }
        }
        const float b0 = db1[c0], b1v = db1[c1];
#pragma unroll
        for (int r = 0; r < FB_R; ++r) {
            sA[r][c0] = acc0[r] + b0;
            sA[r][c1] = acc1[r] + b1v;
        }
    }
    __syncthreads();
    fb_ln_silu(sA, dg1, dbe1, t);
    __syncthreads();
    fb_gemmK<H>(sA, sB, dW2, db2, t);
    __syncthreads();
    fb_ln_silu(sB, dg2, dbe2, t);
    __syncthreads();
    {
        const int c = t & 63;
        const int rb = t >> 6;
        float acc[4] = {0.f, 0.f, 0.f, 0.f};
        for (int k = 0; k < H; k += 4) {
            const float w0 = dW3[(k + 0) * NX + c];
            const float w1 = dW3[(k + 1) * NX + c];
            const float w2 = dW3[(k + 2) * NX + c];
            const float w3 = dW3[(k + 3) * NX + c];
#pragma unroll
            for (int i = 0; i < 4; ++i) {
                const int r = rb + 4 * i;
                const float4 h = *(const float4*)&sB[r][k];
                acc[i] += h.x * w0 + h.y * w1 + h.z * w2 + h.w * w3;
            }
        }
        const float bb = db3[c];
#pragma unroll
        for (int i = 0; i < 4; ++i) {
            const int r = rb + 4 * i;
            out[(row0 + r) * NX + c] = acc[i] + bb;
        }
    }
}

extern "C" void kernel_launch(void* const* d_in, const int* in_sizes, int n_in,
                              void* d_out, int out_size, void* d_ws, size_t ws_size,
                              hipStream_t stream) {
    const float* x0    = (const float*)d_in[0];
    const float* logdt = (const float*)d_in[1];
    const float* eW1  = (const float*)d_in[4];
    const float* eb1  = (const float*)d_in[5];
    const float* eg1  = (const float*)d_in[6];
    const float* ebe1 = (const float*)d_in[7];
    const float* eW2  = (const float*)d_in[8];
    const float* eb2  = (const float*)d_in[9];
    const float* eg2  = (const float*)d_in[10];
    const float* ebe2 = (const float*)d_in[11];
    const float* eW3  = (const float*)d_in[12];
    const float* eb3  = (const float*)d_in[13];
    const float* dW1  = (const float*)d_in[14];
    const float* db1  = (const float*)d_in[15];
    const float* dg1  = (const float*)d_in[16];
    const float* dbe1 = (const float*)d_in[17];
    const float* dW2  = (const float*)d_in[18];
    const float* db2  = (const float*)d_in[19];
    const float* dg2  = (const float*)d_in[20];
    const float* dbe2 = (const float*)d_in[21];
    const float* dW3  = (const float*)d_in[22];
    const float* db3  = (const float*)d_in[23];
    const float* Xi   = (const float*)d_in[24];
    float* out = (float*)d_out;

    if (ws_size >= WS_NEW_BYTES) {
        short* wsb = (short*)d_ws;
        float* zt = (float*)((char*)d_ws + ZT_OFF_BYTES);
        prep_weights<<<WS_ELEMS2 / 256, 256, 0, stream>>>(eW1, eW2, dW2, dW3, eW3, wsb);
        sindy_enc_kernel<<<B_TOTAL / BM, NTH, 0, stream>>>(
            x0, logdt, eb1, eg1, ebe1, eb2, eg2, ebe2, eb3, Xi, wsb, zt);
        sindy_dec_kernel<<<B_TOTAL / BM, NTH, 0, stream>>>(
            zt, dW1, db1, dg1, dbe1, db2, dg2, dbe2, db3, wsb, out);
    } else {
        sindy_fallback_kernel<<<B_TOTAL / FB_R, FB_NT, 0, stream>>>(
            x0, logdt, eW1, eb1, eg1, ebe1, eW2, eb2, eg2, ebe2, eW3, eb3,
            dW1, db1, dg1, dbe1, dW2, db2, dg2, dbe2, dW3, db3, Xi, out);
    }
}

// Round 8
// 469.435 us; speedup vs baseline: 1.5880x; 1.5880x over previous
//
#include <hip/hip_runtime.h>
#include <hip/hip_bf16.h>
#include <math.h>

#define B_TOTAL 131072
#define NX 64
#define H 512
#define LD 8
#define NT 45          // 1 + 8 + 36
#define NSTEPS 20

#define NTH 512        // 8 waves
#define BM 64          // rows per block
#define ASTR 520       // bf16 elements per activation row (1040B stride: 2-way bank alias only)

// ws layout (bf16 elements). GEMM weights are K-CHUNKED: W[kc][n][32], chunk = 32 k-elems.
#define OFF_EW1T 0                    // [2][512][32]   (K=64)
#define OFF_EW2T 32768                // [16][512][32]
#define OFF_DW2T 294912               // [16][512][32]
#define OFF_DW3T 557056               // [16][64][32]
#define WS_ELEMS 589824
#define OFF_W3HI 589824               // [16][512] flat: bf16 hi part of eW3^T (rows 8..15 zero)
#define OFF_W3LO 598016               // [16][512] flat: bf16 lo correction
#define WS_ELEMS2 606208
#define OFF_DW1P 606208               // [512][32] hi/lo packed dW1 panel: slots [wh|wl|wh|wl]
#define WS_ELEMS3 622592              // * 2 bytes
#define ZT_OFF_BYTES (WS_ELEMS3 * 2)
#define WS_NEW_BYTES (ZT_OFF_BYTES + (size_t)B_TOTAL * LD * 4)

typedef __attribute__((ext_vector_type(8))) short short8;
typedef __attribute__((ext_vector_type(4))) float f32x4;

__device__ __forceinline__ ushort f2bf(float f) {
    union { float f; uint u; } v; v.f = f;
    uint u = v.u;
    u += 0x7fff + ((u >> 16) & 1);          // RNE
    return (ushort)(u >> 16);
}
__device__ __forceinline__ float bf2f(ushort s) {
    union { uint u; float f; } v; v.u = ((uint)s) << 16;
    return v.f;
}
__device__ __forceinline__ float silu_f(float v) {
    return v / (1.0f + __expf(-v));
}

// ---------------- weight prep: fp32 row-major [k][n] -> bf16 chunked W^T [kc][n][32] ----------------
__global__ void prep_weights(const float* __restrict__ eW1, const float* __restrict__ eW2,
                             const float* __restrict__ dW2, const float* __restrict__ dW3,
                             const float* __restrict__ eW3, const float* __restrict__ dW1,
                             short* __restrict__ ws) {
    const int id = blockIdx.x * 256 + threadIdx.x;
    if (id < OFF_EW2T) {                               // eW1c [2][512][32]
        const int kc = id >> 14, n = (id >> 5) & 511, kk = id & 31;
        ws[id] = (short)f2bf(eW1[(kc * 32 + kk) * H + n]);
    } else if (id < OFF_DW2T) {                        // eW2c [16][512][32]
        const int j = id - OFF_EW2T;
        const int kc = j >> 14, n = (j >> 5) & 511, kk = j & 31;
        ws[id] = (short)f2bf(eW2[(kc * 32 + kk) * H + n]);
    } else if (id < OFF_DW3T) {                        // dW2c [16][512][32]
        const int j = id - OFF_DW2T;
        const int kc = j >> 14, n = (j >> 5) & 511, kk = j & 31;
        ws[id] = (short)f2bf(dW2[(kc * 32 + kk) * H + n]);
    } else if (id < WS_ELEMS) {                        // dW3c [16][64][32]
        const int j = id - OFF_DW3T;
        const int kc = j >> 11, n = (j >> 5) & 63, kk = j & 31;
        ws[id] = (short)f2bf(dW3[(kc * 32 + kk) * NX + n]);
    } else if (id < OFF_W3LO) {                        // eW3T hi [16][512] flat
        const int j = id - OFF_W3HI, n = j >> 9, k = j & 511;
        const float v = (n < LD) ? eW3[k * LD + n] : 0.f;
        ws[id] = (short)f2bf(v);
    } else if (id < WS_ELEMS2) {                       // eW3T lo
        const int j = id - OFF_W3LO, n = j >> 9, k = j & 511;
        const float v = (n < LD) ? eW3[k * LD + n] : 0.f;
        const float hi = bf2f(f2bf(v));
        ws[id] = (short)f2bf(v - hi);
    } else if (id < WS_ELEMS3) {                       // dW1 packed [512][32]: k-slots [wh|wl|wh|wl]
        const int j = id - OFF_DW1P;
        const int n = j >> 5, s = j & 31;
        const int k = s & 7;
        const float v = dW1[k * H + n];
        const ushort hi = f2bf(v);
        ws[id] = (((s >> 3) & 1) == 0) ? (short)hi : (short)f2bf(v - bf2f(hi));
    }
}

// ---------------- GEMM: act[64][K] (LDS bf16) x W(KxN) via chunked W^T; 1x8 wave grid ----------------
// Wave w owns all 64 rows x cols [w*64, w*64+64): B loaded ONCE per block, contiguous 1KB segments.
// SINGLE-buffered B (b[4] = 32 arch regs): arch pressure ~55 < 64 (128 unified - 64 AGPR acc)
// at launch_bounds(512,4). Latency hiding via TLP (16 waves/CU), not register ping-pong.
template <int K, int N>
__device__ __forceinline__ void gemm_chunked(const short (*act)[ASTR], const short* __restrict__ WTc,
                                             f32x4 (&acc)[4][4], int w, int lm, int q) {
    constexpr int NC = K / 32;
    constexpr int CS = N * 32;
    const short* bp = WTc + (w * 64 + lm) * 32 + q * 8;
#pragma unroll 1
    for (int kc = 0; kc < NC; ++kc) {
        short8 b[4];
        const short* p = bp + kc * CS;
#pragma unroll
        for (int tt = 0; tt < 4; ++tt) b[tt] = *(const short8*)(p + tt * 512);
        const int k0 = kc * 32 + q * 8;
#pragma unroll
        for (int mt = 0; mt < 4; ++mt) {
            short8 a = *(const short8*)&act[mt * 16 + lm][k0];
#pragma unroll
            for (int tt = 0; tt < 4; ++tt)
                acc[mt][tt] = __builtin_amdgcn_mfma_f32_16x16x32_bf16(a, b[tt], acc[mt][tt], 0, 0, 0);
        }
    }
}

// ---------------- bias + LayerNorm + SiLU epilogue, 1x8 grid, per-mt sums (low reg pressure) ----------------
// C-layout: value (row = mt*16 + q*4 + r, col = w*64 + tt*16 + lm). In-place safe (stores after barriers).
__device__ __forceinline__ void ln_epi64(f32x4 (&acc)[4][4],
        const float* __restrict__ bias, const float* __restrict__ g, const float* __restrict__ be,
        short (*act)[ASTR], float (*p1)[8], float (*p2)[8], float (*rstat)[2],
        int w, int lane, int tid) {
    const int lm = lane & 15, q = lane >> 4;
    float cb[4], cg[4], cbe[4];
#pragma unroll
    for (int tt = 0; tt < 4; ++tt) {
        const int c = w * 64 + tt * 16 + lm;
        cb[tt] = bias[c]; cg[tt] = g[c]; cbe[tt] = be[c];
    }
#pragma unroll
    for (int mt = 0; mt < 4; ++mt) {
        float s1[4] = {0.f, 0.f, 0.f, 0.f}, s2[4] = {0.f, 0.f, 0.f, 0.f};
#pragma unroll
        for (int tt = 0; tt < 4; ++tt)
#pragma unroll
            for (int r = 0; r < 4; ++r) {
                float v = acc[mt][tt][r] + cb[tt];
                acc[mt][tt][r] = v;
                s1[r] += v;
                s2[r] += v * v;
            }
#pragma unroll
        for (int m = 1; m < 16; m <<= 1) {
#pragma unroll
            for (int r = 0; r < 4; ++r) {
                s1[r] += __shfl_xor(s1[r], m);
                s2[r] += __shfl_xor(s2[r], m);
            }
        }
        if (lm == 0) {
#pragma unroll
            for (int r = 0; r < 4; ++r) {
                const int row = mt * 16 + q * 4 + r;
                p1[row][w] = s1[r];
                p2[row][w] = s2[r];
            }
        }
    }
    __syncthreads();
    if (tid < BM) {
        float a = 0.f, b2 = 0.f;
#pragma unroll
        for (int j = 0; j < 8; ++j) { a += p1[tid][j]; b2 += p2[tid][j]; }
        const float mean = a * (1.0f / H);
        rstat[tid][0] = mean;
        rstat[tid][1] = rsqrtf(b2 * (1.0f / H) - mean * mean + 1e-5f);
    }
    __syncthreads();
#pragma unroll
    for (int mt = 0; mt < 4; ++mt) {
#pragma unroll
        for (int r = 0; r < 4; ++r) {
            const int row = mt * 16 + q * 4 + r;
            const float mu = rstat[row][0], rs = rstat[row][1];
#pragma unroll
            for (int tt = 0; tt < 4; ++tt) {
                const float v = (acc[mt][tt][r] - mu) * rs * cg[tt] + cbe[tt];
                act[row][w * 64 + tt * 16 + lm] = (short)f2bf(silu_f(v));
            }
        }
    }
    __syncthreads();
}

// ==================== K1: x0 -> encoder -> Euler -> z_t ====================
__global__ __launch_bounds__(NTH, 4) void sindy_enc_kernel(
        const float* __restrict__ x0, const float* __restrict__ logdt,
        const float* __restrict__ eb1, const float* __restrict__ eg1, const float* __restrict__ ebe1,
        const float* __restrict__ eb2, const float* __restrict__ eg2, const float* __restrict__ ebe2,
        const float* __restrict__ eb3, const float* __restrict__ Xi,
        const short* __restrict__ wsb, float* __restrict__ zt) {
    __shared__ __align__(16) short act[BM][ASTR];          // 66,560 B
    __shared__ __align__(16) float scratch[2048];          // 8 KB: p1|p2 or partial[4][64][8]
    __shared__ float rstat[BM][2];
    __shared__ float dtb[BM];
    __shared__ float xis[NT * LD];
    float (*p1)[8] = (float(*)[8])scratch;                       // [64][8]
    float (*p2)[8] = (float(*)[8])(scratch + 512);               // [64][8]
    float (*partial)[BM][LD] = (float(*)[BM][LD])scratch;        // [4][64][8] (time-disjoint)

    const int tid = threadIdx.x;
    const int w = tid >> 6, lane = tid & 63, lm = lane & 15, q = lane >> 4;
    const int row0 = blockIdx.x * BM;

    if (tid < NT * LD) xis[tid] = Xi[tid];
    if (tid < BM) dtb[tid] = logdt[row0 + tid] * (1.0f / NSTEPS);
    {   // stage x0 tile fp32 -> bf16 LDS (64 rows x 64 cols), coalesced
        const int r = tid >> 3, c8 = (tid & 7) * 8;
        const float* xr = &x0[(row0 + r) * NX + c8];
        const float4 va = *(const float4*)xr;
        const float4 vb = *(const float4*)(xr + 4);
        short8 sv;
        sv[0] = (short)f2bf(va.x); sv[1] = (short)f2bf(va.y);
        sv[2] = (short)f2bf(va.z); sv[3] = (short)f2bf(va.w);
        sv[4] = (short)f2bf(vb.x); sv[5] = (short)f2bf(vb.y);
        sv[6] = (short)f2bf(vb.z); sv[7] = (short)f2bf(vb.w);
        *(short8*)&act[r][c8] = sv;
    }
    __syncthreads();

    // ---- enc1: 64 -> 512 ----
    {
        f32x4 acc[4][4];
#pragma unroll
        for (int mt = 0; mt < 4; ++mt)
#pragma unroll
            for (int tt = 0; tt < 4; ++tt) acc[mt][tt] = (f32x4){0.f, 0.f, 0.f, 0.f};
        gemm_chunked<NX, H>(act, wsb + OFF_EW1T, acc, w, lm, q);
        ln_epi64(acc, eb1, eg1, ebe1, act, p1, p2, rstat, w, lane, tid);
    }

    // ---- enc2: 512 -> 512 ----
    {
        f32x4 acc[4][4];
#pragma unroll
        for (int mt = 0; mt < 4; ++mt)
#pragma unroll
            for (int tt = 0; tt < 4; ++tt) acc[mt][tt] = (f32x4){0.f, 0.f, 0.f, 0.f};
        gemm_chunked<H, H>(act, wsb + OFF_EW2T, acc, w, lm, q);
        ln_epi64(acc, eb2, eg2, ebe2, act, p1, p2, rstat, w, lane, tid);
    }

    // ---- enc3: 512 -> 8 via MFMA, hi/lo bf16 weight split (~fp32 weight precision) ----
    // wave w: kq = w&3 (128 k), mh = w>>2 (2 m-tile pairs). 16 MFMA/wave.
    float z0;
    {
        const short* W3H = wsb + OFF_W3HI;
        const short* W3L = wsb + OFF_W3LO;
        const int kq = w & 3, mh = w >> 2;
        f32x4 a3[2];
        a3[0] = (f32x4){0.f, 0.f, 0.f, 0.f};
        a3[1] = (f32x4){0.f, 0.f, 0.f, 0.f};
#pragma unroll
        for (int kc = 0; kc < 4; ++kc) {
            const int k0 = kq * 128 + kc * 32 + q * 8;
            short8 bh = *(const short8*)&W3H[lm * H + k0];
            short8 bl = *(const short8*)&W3L[lm * H + k0];
#pragma unroll
            for (int i = 0; i < 2; ++i) {
                short8 a = *(const short8*)&act[(mh * 2 + i) * 16 + lm][k0];
                a3[i] = __builtin_amdgcn_mfma_f32_16x16x32_bf16(a, bh, a3[i], 0, 0, 0);
                a3[i] = __builtin_amdgcn_mfma_f32_16x16x32_bf16(a, bl, a3[i], 0, 0, 0);
            }
        }
        if (lm < 8) {
#pragma unroll
            for (int i = 0; i < 2; ++i)
#pragma unroll
                for (int r = 0; r < 4; ++r)
                    partial[kq][(mh * 2 + i) * 16 + q * 4 + r][lm] = a3[i][r];
        }
        __syncthreads();
        {
            const int r = tid >> 3, c = tid & 7;
            const float s = partial[0][r][c] + partial[1][r][c] +
                            partial[2][r][c] + partial[3][r][c];
            z0 = tanhf(s + eb3[c]);
        }
    }

    // ---- SINDy Euler: barrier-free; linear coeffs in regs, quad coeffs from LDS ----
    // (keeps Euler live-set ~25 arch regs: no pressure against the 64-arch cap)
    {
        const int r = tid >> 3, c = tid & 7;
        const int lbase = lane & ~7;
        float xrl[1 + LD];
#pragma unroll
        for (int t = 0; t <= LD; ++t) xrl[t] = xis[t * LD + c];
        const float dtv = dtb[r];
        float zc = z0;
        for (int st = 0; st < NSTEPS; ++st) {
            float z[LD];
#pragma unroll
            for (int j = 0; j < LD; ++j) z[j] = __shfl(zc, lbase + j);
            float zd = xrl[0];
#pragma unroll
            for (int j = 0; j < LD; ++j) zd += z[j] * xrl[1 + j];
            int idx = 1 + LD;
#pragma unroll
            for (int i = 0; i < LD; ++i)
#pragma unroll
                for (int j = i; j < LD; ++j) {
                    zd += z[i] * z[j] * xis[idx * LD + c];
                    ++idx;
                }
            zc += zd * dtv;
        }
        zt[row0 * LD + tid] = zc;   // coalesced
    }
}

// ==================== K2: z_t -> decoder -> out ====================
__global__ __launch_bounds__(NTH, 4) void sindy_dec_kernel(
        const float* __restrict__ zt,
        const float* __restrict__ db1,
        const float* __restrict__ dg1, const float* __restrict__ dbe1,
        const float* __restrict__ db2, const float* __restrict__ dg2, const float* __restrict__ dbe2,
        const float* __restrict__ db3,
        const short* __restrict__ wsb, float* __restrict__ out) {
    __shared__ __align__(16) short act[BM][ASTR];
    __shared__ float p1[BM][8], p2[BM][8], rstat[BM][2];
    __shared__ __align__(16) float zbuf[BM][LD];
    const int tid = threadIdx.x;
    const int w = tid >> 6, lane = tid & 63, lm = lane & 15, q = lane >> 4;
    const int row0 = blockIdx.x * BM;

    ((float*)zbuf)[tid] = zt[row0 * LD + tid];
    __syncthreads();

    // ---- dec1: 8 -> 512 via MFMA, hi/lo packed K=32 frags (~fp32 precision) ----
    // A = [zh,zh,zl,zl] (q selects), B = [wh,wl,wh,wl] -> sum = (zh+zl)(wh+wl) ~= z*w exactly.
    // acc is MFMA-produced -> AGPR; arch stays low.
    {
        const short* bp = wsb + OFF_DW1P + (w * 64 + lm) * 32 + q * 8;
        short8 b[4];
#pragma unroll
        for (int tt = 0; tt < 4; ++tt) b[tt] = *(const short8*)(bp + tt * 512);
        f32x4 acc[4][4];
#pragma unroll
        for (int mt = 0; mt < 4; ++mt) {
            const int row = mt * 16 + lm;
            const float4 za = *(const float4*)&zbuf[row][0];
            const float4 zb = *(const float4*)&zbuf[row][4];
            float zv[LD] = {za.x, za.y, za.z, za.w, zb.x, zb.y, zb.z, zb.w};
            short8 a;
#pragma unroll
            for (int j = 0; j < LD; ++j) {
                const ushort h = f2bf(zv[j]);
                a[j] = (q < 2) ? (short)h : (short)f2bf(zv[j] - bf2f(h));
            }
#pragma unroll
            for (int tt = 0; tt < 4; ++tt)
                acc[mt][tt] = __builtin_amdgcn_mfma_f32_16x16x32_bf16(
                    a, b[tt], (f32x4){0.f, 0.f, 0.f, 0.f}, 0, 0, 0);
        }
        ln_epi64(acc, db1, dg1, dbe1, act, p1, p2, rstat, w, lane, tid);
    }

    // ---- dec2: 512 -> 512 ----
    {
        f32x4 acc[4][4];
#pragma unroll
        for (int mt = 0; mt < 4; ++mt)
#pragma unroll
            for (int tt = 0; tt < 4; ++tt) acc[mt][tt] = (f32x4){0.f, 0.f, 0.f, 0.f};
        gemm_chunked<H, H>(act, wsb + OFF_DW2T, acc, w, lm, q);
        ln_epi64(acc, db2, dg2, dbe2, act, p1, p2, rstat, w, lane, tid);
    }

    // ---- dec3: 512 -> 64 + bias, fp32 out. wave w: nt = w&3, rows (w>>2)*32..+31 ----
    {
        const short* W3c = wsb + OFF_DW3T;
        const int nt = w & 3, mtb = (w >> 2) << 1;
        const short* bp = W3c + (nt * 16 + lm) * 32 + q * 8;
        f32x4 a2[2];
        a2[0] = (f32x4){0.f, 0.f, 0.f, 0.f};
        a2[1] = (f32x4){0.f, 0.f, 0.f, 0.f};
#pragma unroll 1
        for (int kc = 0; kc < 16; ++kc) {
            short8 b = *(const short8*)(bp + kc * 2048);
            const int k0 = kc * 32 + q * 8;
#pragma unroll
            for (int i = 0; i < 2; ++i) {
                short8 a = *(const short8*)&act[(mtb + i) * 16 + lm][k0];
                a2[i] = __builtin_amdgcn_mfma_f32_16x16x32_bf16(a, b, a2[i], 0, 0, 0);
            }
        }
        const int c = nt * 16 + lm;
        const float bb = db3[c];
#pragma unroll
        for (int i = 0; i < 2; ++i)
#pragma unroll
            for (int r = 0; r < 4; ++r) {
                const int row = (mtb + i) * 16 + q * 4 + r;
                out[(row0 + row) * NX + c] = a2[i][r] + bb;
            }
    }
}

// =================== fallback (fp32 kernel, no ws needed) ===================
#define FB_R 16
#define FB_STRIDE 520
#define FB_NT 256

__device__ __forceinline__ void fb_ln_silu(float buf[FB_R][FB_STRIDE],
                                           const float* __restrict__ g,
                                           const float* __restrict__ be, int t) {
    const int r = t >> 4, lane = t & 15;
    float s1 = 0.f, s2 = 0.f;
#pragma unroll
    for (int j = 0; j < H / 16; ++j) {
        float v = buf[r][lane + 16 * j];
        s1 += v; s2 += v * v;
    }
#pragma unroll
    for (int m = 8; m >= 1; m >>= 1) {
        s1 += __shfl_xor(s1, m, 16);
        s2 += __shfl_xor(s2, m, 16);
    }
    const float mean = s1 * (1.0f / H);
    const float var = s2 * (1.0f / H) - mean * mean;
    const float rstd = rsqrtf(var + 1e-5f);
#pragma unroll
    for (int j = 0; j < H / 16; ++j) {
        const int c = lane + 16 * j;
        float v = buf[r][c];
        buf[r][c] = silu_f((v - mean) * rstd * g[c] + be[c]);
    }
}

template <int K>
__device__ __forceinline__ void fb_gemmK(const float in[FB_R][FB_STRIDE], float out[FB_R][FB_STRIDE],
                                         const float* __restrict__ W,
                                         const float* __restrict__ b, int t) {
    const int c0 = t, c1 = t + 256;
    float acc0[FB_R], acc1[FB_R];
#pragma unroll
    for (int r = 0; r < FB_R; ++r) { acc0[r] = 0.f; acc1[r] = 0.f; }
    for (int k = 0; k < K; k += 4) {
        const float w00 = W[(k + 0) * H + c0], w10 = W[(k + 0) * H + c1];
        const float w01 = W[(k + 1) * H + c0], w11 = W[(k + 1) * H + c1];
        const float w02 = W[(k + 2) * H + c0], w12 = W[(k + 2) * H + c1];
        const float w03 = W[(k + 3) * H + c0], w13 = W[(k + 3) * H + c1];
#pragma unroll
        for (int r = 0; r < FB_R; ++r) {
            const float4 h = *(const float4*)&in[r][k];
            acc0[r] += h.x * w00 + h.y * w01 + h.z * w02 + h.w * w03;
            acc1[r] += h.x * w10 + h.y * w11 + h.z * w12 + h.w * w13;
        }
    }
    const float b0 = b[c0], b1 = b[c1];
#pragma unroll
    for (int r = 0; r < FB_R; ++r) {
        out[r][c0] = acc0[r] + b0;
        out[r][c1] = acc1[r] + b1;
    }
}

__global__ __launch_bounds__(FB_NT, 2) void sindy_fallback_kernel(
    const float* __restrict__ x0, const float* __restrict__ logdt,
    const float* __restrict__ eW1, const float* __restrict__ eb1,
    const float* __restrict__ eg1, const float* __restrict__ ebe1,
    const float* __restrict__ eW2, const float* __restrict__ eb2,
    const float* __restrict__ eg2, const float* __restrict__ ebe2,
    const float* __restrict__ eW3, const float* __restrict__ eb3,
    const float* __restrict__ dW1, const float* __restrict__ db1,
    const float* __restrict__ dg1, const float* __restrict__ dbe1,
    const float* __restrict__ dW2, const float* __restrict__ db2,
    const float* __restrict__ dg2, const float* __restrict__ dbe2,
    const float* __restrict__ dW3, const float* __restrict__ db3,
    const float* __restrict__ Xi, float* __restrict__ out) {
    __shared__ float sA[FB_R][FB_STRIDE];
    __shared__ float sB[FB_R][FB_STRIDE];
    __shared__ float zbuf[FB_R][LD];
    __shared__ float dtb[FB_R];
    __shared__ float xis[NT * LD];

    const int t = threadIdx.x;
    const int row0 = blockIdx.x * FB_R;

    for (int i = t; i < NT * LD; i += FB_NT) xis[i] = Xi[i];
    if (t < FB_R) dtb[t] = logdt[row0 + t] * (1.0f / NSTEPS);
    {
        const int r = t >> 4, k4 = (t & 15) * 4;
        *(float4*)&sB[r][k4] = *(const float4*)&x0[(row0 + r) * NX + k4];
    }
    __syncthreads();
    fb_gemmK<NX>(sB, sA, eW1, eb1, t);
    __syncthreads();
    fb_ln_silu(sA, eg1, ebe1, t);
    __syncthreads();
    fb_gemmK<H>(sA, sB, eW2, eb2, t);
    __syncthreads();
    fb_ln_silu(sB, eg2, ebe2, t);
    __syncthreads();
    if (t < FB_R * LD) {
        const int r = t >> 3, c = t & 7;
        float acc = 0.f;
        for (int k = 0; k < H; k += 4) {
            const float4 h = *(const float4*)&sB[r][k];
            acc += h.x * eW3[(k + 0) * LD + c] + h.y * eW3[(k + 1) * LD + c] +
                   h.z * eW3[(k + 2) * LD + c] + h.w * eW3[(k + 3) * LD + c];
        }
        zbuf[r][c] = tanhf(acc + eb3[c]);
    }
    __syncthreads();
    for (int s = 0; s < NSTEPS; ++s) {
        float zn = 0.f;
        const int r = t >> 3, c = t & 7;
        if (t < FB_R * LD) {
            float z[LD];
#pragma unroll
            for (int j = 0; j < LD; ++j) z[j] = zbuf[r][j];
            float zd = xis[c];
#pragma unroll
            for (int j = 0; j < LD; ++j) zd += z[j] * xis[(1 + j) * LD + c];
            int idx = 1 + LD;
#pragma unroll
            for (int i = 0; i < LD; ++i)
#pragma unroll
                for (int j = i; j < LD; ++j) {
                    zd += z[i] * z[j] * xis[idx * LD + c];
                    ++idx;
                }
            zn = z[c] + zd * dtb[r];
        }
        __syncthreads();
        if (t < FB_R * LD) zbuf[r][c] = zn;
        __syncthreads();
    }
    {
        const int c0 = t, c1 = t + 256;
        float acc0[FB_R], acc1[FB_R];
#pragma unroll
        for (int r = 0; r < FB_R; ++r) { acc0[r] = 0.f; acc1[r] = 0.f; }
#pragma unroll
        for (int k = 0; k < LD; ++k) {
            const float w0 = dW1[k * H + c0], w1 = dW1[k * H + c1];
#pragma unroll
            for (int r = 0; r < FB_R; ++r) {
                const float zv = zbuf[r][k];
                acc0[r] += zv * w0;
                acc1[r] += zv * w1;
            }
        }
        const float b0 = db1[c0], b1v = db1[c1];
#pragma unroll
        for (int r = 0; r < FB_R; ++r) {
            sA[r][c0] = acc0[r] + b0;
            sA[r][c1] = acc1[r] + b1v;
        }
    }
    __syncthreads();
    fb_ln_silu(sA, dg1, dbe1, t);
    __syncthreads();
    fb_gemmK<H>(sA, sB, dW2, db2, t);
    __syncthreads();
    fb_ln_silu(sB, dg2, dbe2, t);
    __syncthreads();
    {
        const int c = t & 63;
        const int rb = t >> 6;
        float acc[4] = {0.f, 0.f, 0.f, 0.f};
        for (int k = 0; k < H; k += 4) {
            const float w0 = dW3[(k + 0) * NX + c];
            const float w1 = dW3[(k + 1) * NX + c];
            const float w2 = dW3[(k + 2) * NX + c];
            const float w3 = dW3[(k + 3) * NX + c];
#pragma unroll
            for (int i = 0; i < 4; ++i) {
                const int r = rb + 4 * i;
                const float4 h = *(const float4*)&sB[r][k];
                acc[i] += h.x * w0 + h.y * w1 + h.z * w2 + h.w * w3;
            }
        }
        const float bb = db3[c];
#pragma unroll
        for (int i = 0; i < 4; ++i) {
            const int r = rb + 4 * i;
            out[(row0 + r) * NX + c] = acc[i] + bb;
        }
    }
}

extern "C" void kernel_launch(void* const* d_in, const int* in_sizes, int n_in,
                              void* d_out, int out_size, void* d_ws, size_t ws_size,
                              hipStream_t stream) {
    const float* x0    = (const float*)d_in[0];
    const float* logdt = (const float*)d_in[1];
    const float* eW1  = (const float*)d_in[4];
    const float* eb1  = (const float*)d_in[5];
    const float* eg1  = (const float*)d_in[6];
    const float* ebe1 = (const float*)d_in[7];
    const float* eW2  = (const float*)d_in[8];
    const float* eb2  = (const float*)d_in[9];
    const float* eg2  = (const float*)d_in[10];
    const float* ebe2 = (const float*)d_in[11];
    const float* eW3  = (const float*)d_in[12];
    const float* eb3  = (const float*)d_in[13];
    const float* dW1  = (const float*)d_in[14];
    const float* db1  = (const float*)d_in[15];
    const float* dg1  = (const float*)d_in[16];
    const float* dbe1 = (const float*)d_in[17];
    const float* dW2  = (const float*)d_in[18];
    const float* db2  = (const float*)d_in[19];
    const float* dg2  = (const float*)d_in[20];
    const float* dbe2 = (const float*)d_in[21];
    const float* dW3  = (const float*)d_in[22];
    const float* db3  = (const float*)d_in[23];
    const float* Xi   = (const float*)d_in[24];
    float* out = (float*)d_out;

    if (ws_size >= WS_NEW_BYTES) {
        short* wsb = (short*)d_ws;
        float* zt = (float*)((char*)d_ws + ZT_OFF_BYTES);
        prep_weights<<<WS_ELEMS3 / 256, 256, 0, stream>>>(eW1, eW2, dW2, dW3, eW3, dW1, wsb);
        sindy_enc_kernel<<<B_TOTAL / BM, NTH, 0, stream>>>(
            x0, logdt, eb1, eg1, ebe1, eb2, eg2, ebe2, eb3, Xi, wsb, zt);
        sindy_dec_kernel<<<B_TOTAL / BM, NTH, 0, stream>>>(
            zt, db1, dg1, dbe1, db2, dg2, dbe2, db3, wsb, out);
    } else {
        sindy_fallback_kernel<<<B_TOTAL / FB_R, FB_NT, 0, stream>>>(
            x0, logdt, eW1, eb1, eg1, ebe1, eW2, eb2, eg2, ebe2, eW3, eb3,
            dW1, db1, dg1, dbe1, dW2, db2, dg2, dbe2, dW3, db3, Xi, out);
    }
}